// Round 10
// baseline (1837.318 us; speedup 1.0000x reference)
//
#include <hip/hip_runtime.h>
#include <hip/hip_bf16.h>

using bf16 = __hip_bfloat16;
typedef short bf16x8 __attribute__((ext_vector_type(8)));
typedef float f32x4  __attribute__((ext_vector_type(4)));

static constexpr int Bn = 4, Hn = 512, Wn = 512;
static constexpr int HWn = Hn * Wn;          // 262144
static constexpr int Hp = 514, Wp = 514;
static constexpr int QN = Hp * Wp;           // 264196 (1-px halo all around)
static constexpr int QN8 = QN * 8;           // elements per 8-channel plane
static constexpr int Kn = 11, PADk = 5;

__device__ __forceinline__ float b2f(bf16 v) { return __bfloat162float(v); }
__device__ __forceinline__ bf16  f2b(float v) { return __float2bfloat16(v); }

// ---------------------------------------------------------------------------
// Feature layout: plane-split NHW,C8 — [C/8 planes][QN pixels][8 ch] bf16.
// ---------------------------------------------------------------------------

// Zero the 1-px halo ring of every plane (2052 px/plane).
__global__ __launch_bounds__(256) void zero_halo(bf16* __restrict__ buf, int nplanes)
{
    constexpr int PER = 2 * Wp + 2 * Hn;     // 2052
    int i = blockIdx.x * 256 + threadIdx.x;
    if (i >= nplanes * PER) return;
    int p = i / PER, r = i - p * PER;
    int q;
    if (r < Wp)            q = r;                          // top row
    else if (r < 2 * Wp)   q = (Hp - 1) * Wp + (r - Wp);   // bottom row
    else if (r < 2 * Wp + Hn) q = (r - 2 * Wp + 1) * Wp;   // left col rows 1..512
    else                   q = (r - 2 * Wp - Hn + 1) * Wp + (Wp - 1); // right col
    *(uint4*)(buf + (size_t)p * QN8 + (size_t)q * 8) = uint4{0u, 0u, 0u, 0u};
}

// Pack concat(rgb, depth, 0,0,0,0) -> plane 0 of xin ([QN][8]); halo = 0.
__global__ __launch_bounds__(256) void pack8(
    const float* __restrict__ rgb, const float* __restrict__ depth,
    bf16* __restrict__ xin)
{
    int q = blockIdx.x * 256 + threadIdx.x;
    if (q >= QN) return;
    int yy = q / Wp, xx = q - yy * Wp;
    float r = 0.f, g = 0.f, b = 0.f, d = 0.f;
    if (yy >= 1 && yy <= Hn && xx >= 1 && xx <= Wn) {
        int px = (yy - 1) * Wn + (xx - 1);
        r = rgb[px]; g = rgb[HWn + px]; b = rgb[2 * HWn + px]; d = depth[px];
    }
    auto pk = [](float a, float c) {
        return (unsigned)__builtin_bit_cast(unsigned short, __float2bfloat16(a)) |
               ((unsigned)__builtin_bit_cast(unsigned short, __float2bfloat16(c)) << 16);
    };
    uint4 o; o.x = pk(r, g); o.y = pk(b, d); o.z = 0u; o.w = 0u;
    *(uint4*)(xin + (size_t)q * 8) = o;
}

// ---------------------------------------------------------------------------
// Weight prep: OIHW f32 -> MFMA-fragment-ordered bf16.
// dst[ ((ks*NCB + c16b)*64 + lane)*8 + j ] = wt[co][k] where
//   co = c16b*16 + (lane&15), k = ks*32 + (lane>>4)*8 + j, k = tap*CINP + ci.
// ---------------------------------------------------------------------------
__global__ void prep_wtF(const float* __restrict__ w, bf16* __restrict__ dst,
                         int COUT, int CIN, int CINP, int TAPSP)
{
    int K = CINP * TAPSP, NCB = COUT / 16;
    int idx = blockIdx.x * 256 + threadIdx.x;
    if (idx >= COUT * K) return;
    int j = idx & 7, lane = (idx >> 3) & 63;
    int rest = idx >> 9;
    int c16b = rest % NCB, ks = rest / NCB;
    int co = c16b * 16 + (lane & 15);
    int k  = ks * 32 + (lane >> 4) * 8 + j;
    int tap = k / CINP, ci = k - tap * CINP;
    float v = (tap < 9 && ci < CIN) ? w[((size_t)co * CIN + ci) * 9 + tap] : 0.f;
    dst[idx] = f2b(v);
}

// wh (rows 0-10) + wv (rows 11-21) + zero (22-31), fragment-ordered [32][576]
__global__ void prep_hvF(const float* __restrict__ wh, const float* __restrict__ wv,
                         bf16* __restrict__ dst)
{
    int idx = blockIdx.x * 256 + threadIdx.x;
    if (idx >= 32 * 576) return;
    int j = idx & 7, lane = (idx >> 3) & 63;
    int rest = idx >> 9;
    int c16b = rest & 1, ks = rest >> 1;       // NCB = 2
    int co = c16b * 16 + (lane & 15);
    int k  = ks * 32 + (lane >> 4) * 8 + j;
    int tap = k / 64, ci = k & 63;
    float v = 0.f;
    if (tap < 9) {
        if (co < 11)      v = wh[((size_t)co * 64 + ci) * 9 + tap];
        else if (co < 22) v = wv[((size_t)(co - 11) * 64 + ci) * 9 + tap];
    }
    dst[idx] = f2b(v);
}

__global__ void prep_bias_hv(const float* __restrict__ bh, const float* __restrict__ bv,
                             float* __restrict__ dst)
{
    int i = threadIdx.x;
    if (i < 32) dst[i] = (i < 11) ? bh[i] : ((i < 22) ? bv[i - 11] : 0.f);
}

// ---------------------------------------------------------------------------
// Implicit-GEMM 3x3 conv via MFMA 16x16x32 bf16 — barrier-free K-loop,
// A-prefetch 3-deep / B-prefetch 2-deep, small wave tile for occupancy.
//   in:  plane-split [CINP/8][QN][8] bf16   out: plane-split [COUT/8][QN][8]
// Block: 256 thr = 4 waves. Wave tile: NFM*16 px x NFN*16 co (64x64).
// COUT=128: waves split 2x2 over (px, co); COUT<=64: 4 waves stacked on px.
// acc 64 + A 48 + B 32 + addr ~= 170 VGPR -> 3 waves/SIMD (launch_bounds).
// Epilogue: LDS plane-major tile (32 KB) -> contiguous uint4 stores.
// ---------------------------------------------------------------------------
template<int CINP, int COUT, int TAPSP, int NFM, bool RELU, bool OUTF32>
__global__ __launch_bounds__(256, 3) void conv_gemm(
    const bf16* __restrict__ in, const bf16* __restrict__ wtF,
    const float* __restrict__ bias, void* __restrict__ outv)
{
    constexpr int K    = CINP * TAPSP;
    constexpr int NK   = K / 32;
    constexpr int NCB  = COUT / 16;
    constexpr int NWN  = (COUT == 128) ? 2 : 1;   // waves along co
    constexpr int NWM  = 4 / NWN;                 // waves along px
    constexpr int NFN  = NCB / NWN;               // co frags per wave (4,4,2)
    constexpr int BM   = NWM * NFM * 16;          // block px (256 or 128)
    constexpr int GX   = 512 / BM;
    constexpr int OSZ  = OUTF32 ? 4 : 2;
    constexpr int TILEB = BM * COUT * OSZ;        // 32 KB everywhere
    constexpr int PCB  = BM * 8 * OSZ;            // bytes per output plane chunk

    __shared__ char smem[TILEB];                  // epilogue staging only

    const int tid  = threadIdx.x;
    const int lane = tid & 63, wid = tid >> 6;
    const int l15  = lane & 15, l4 = lane >> 4;
    const int wmi  = (NWN == 2) ? (wid & 1) : wid;
    const int wni  = (NWN == 2) ? (wid >> 1) : 0;
    const int cbb  = wni * NFN;                   // co-16-block base

    // XCD-band swizzle: XCD k owns a contiguous band of rows (nwg % 8 == 0)
    const int nwg  = GX * 512;
    int orig = (int)blockIdx.y * GX + (int)blockIdx.x;
    int sbid = (orig & 7) * (nwg >> 3) + (orig >> 3);
    const int bx = (GX == 1) ? 0 : (sbid & (GX - 1));
    const int by = (GX == 1) ? sbid : (sbid / GX);

    const int qblk = (by + 1) * Wp + 1 + bx * BM;   // block's first pixel
    const int q0   = qblk + wmi * (NFM * 16);       // wave's first pixel

    // A base element offsets per m-frag (plane term from l4 unless CINP==8)
    int abase[NFM];
#pragma unroll
    for (int mf = 0; mf < NFM; ++mf) {
        int q = q0 + mf * 16 + l15;
        abase[mf] = q * 8 + ((CINP == 8) ? 0 : l4 * QN8);
    }

    auto loadA = [&](int ks, bf16x8 (&a)[NFM]) {
        if constexpr (CINP == 8) {
            int tap = ks * 4 + l4;                 // per-lane tap
            int dy  = tap / 3;
            int off = (tap < 9) ? (dy - 1) * Wp + (tap - dy * 3 - 1) : 0;
#pragma unroll
            for (int mf = 0; mf < NFM; ++mf)
                a[mf] = *(const bf16x8*)(in + abase[mf] + off * 8);
        } else {
            const int kk  = ks * 32;
            const int tap = kk / CINP;
            const int cib = kk - tap * CINP;
            const int pb  = cib >> 3;              // base plane of this k-chunk
            const int dy  = tap / 3;
            const int off = (dy - 1) * Wp + (tap - dy * 3 - 1);
            const int stp = pb * QN8 + off * 8;
#pragma unroll
            for (int mf = 0; mf < NFM; ++mf)
                a[mf] = *(const bf16x8*)(in + abase[mf] + stp);
        }
    };
    auto loadB = [&](int ks, bf16x8 (&bfr)[NFN]) {
        const bf16* bp = wtF + lane * 8;
#pragma unroll
        for (int nf = 0; nf < NFN; ++nf)
            bfr[nf] = *(const bf16x8*)(bp + (size_t)(ks * NCB + cbb + nf) * 512);
    };

    f32x4 acc[NFM][NFN];
#pragma unroll
    for (int mf = 0; mf < NFM; ++mf)
#pragma unroll
        for (int nf = 0; nf < NFN; ++nf) acc[mf][nf] = f32x4{0.f, 0.f, 0.f, 0.f};

    auto step = [&](bf16x8 (&a)[NFM], bf16x8 (&bfr)[NFN]) {
#pragma unroll
        for (int mf = 0; mf < NFM; ++mf)
#pragma unroll
            for (int nf = 0; nf < NFN; ++nf)
                acc[mf][nf] = __builtin_amdgcn_mfma_f32_16x16x32_bf16(
                    a[mf], bfr[nf], acc[mf][nf], 0, 0, 0);
    };

    if constexpr (NK >= 12 && NK % 6 == 0) {
        // A 3-deep, B 2-deep rotation; period lcm(3,2)=6; no barriers.
        bf16x8 a0[NFM], a1[NFM], a2[NFM], b0[NFN], b1[NFN];
        loadA(0, a0); loadB(0, b0);
        loadA(1, a1); loadB(1, b1);
        loadA(2, a2);
        int ks = 0;
        for (; ks + 6 < NK; ks += 6) {
            step(a0, b0); loadA(ks + 3, a0); loadB(ks + 2, b0);
            step(a1, b1); loadA(ks + 4, a1); loadB(ks + 3, b1);
            step(a2, b0); loadA(ks + 5, a2); loadB(ks + 4, b0);
            step(a0, b1); loadA(ks + 6, a0); loadB(ks + 5, b1);
            step(a1, b0); loadA(ks + 7, a1); loadB(ks + 6, b0);
            step(a2, b1); loadA(ks + 8, a2); loadB(ks + 7, b1);
        }
        // final 6 steps (ks == NK-6): drain, no out-of-range loads
        step(a0, b0); loadA(ks + 3, a0); loadB(ks + 2, b0);
        step(a1, b1); loadA(ks + 4, a1); loadB(ks + 3, b1);
        step(a2, b0); loadA(ks + 5, a2); loadB(ks + 4, b0);
        step(a0, b1); loadB(ks + 5, b1);
        step(a1, b0);
        step(a2, b1);
    } else {
        // small-NK fallback: 2-deep double buffer
        bf16x8 a0[NFM], a1[NFM], b0[NFN], b1[NFN];
        loadA(0, a0); loadB(0, b0);
        for (int ks = 0; ks + 1 < NK; ks += 2) {
            loadA(ks + 1, a1); loadB(ks + 1, b1);
            step(a0, b0);
            if (ks + 2 < NK) { loadA(ks + 2, a0); loadB(ks + 2, b0); }
            step(a1, b1);
        }
        if constexpr (NK & 1) step(a0, b0);
    }

    // ---- epilogue: bias (+relu) -> LDS plane-major tile -> chunk stores ----
#pragma unroll
    for (int nf = 0; nf < NFN; ++nf) {
        const int co = (cbb + nf) * 16 + l15;
        const float bv = bias[co];
#pragma unroll
        for (int mf = 0; mf < NFM; ++mf) {
#pragma unroll
            for (int r = 0; r < 4; ++r) {
                float v = acc[mf][nf][r] + bv;
                if constexpr (RELU) v = fmaxf(v, 0.f);
                const int pl = wmi * (NFM * 16) + mf * 16 + l4 * 4 + r;  // local px
                const int eo = ((co >> 3) * BM + pl) * 8 + (co & 7);
                if constexpr (OUTF32)
                    ((float*)smem)[eo] = v;
                else
                    ((bf16*)smem)[eo] = f2b(v);
            }
        }
    }
    __syncthreads();
    // each output plane chunk = BM consecutive pixels x 8 ch = contiguous span
    char* gbase = (char*)outv;
    for (int ofs = tid * 16; ofs < TILEB; ofs += 4096) {
        const int p = ofs / PCB, w = ofs - p * PCB;
        char* dst = gbase + ((size_t)p * QN8 + (size_t)qblk * 8) * OSZ + w;
        *(uint4*)dst = *(const uint4*)(smem + ofs);
    }
}

// ---------------------------------------------------------------------------
// Softmax over the 11+11 logit channels (4 f32 planes) -> [px][12] f32 maps
// ---------------------------------------------------------------------------
__global__ __launch_bounds__(256) void softmax_hv(
    const float* __restrict__ logits, float* __restrict__ khI, float* __restrict__ kvI)
{
    int px = blockIdx.x * 256 + threadIdx.x;   // over HW exact
    int y = px >> 9, x = px & (Wn - 1);
    int q = (y + 1) * Wp + x + 1;
    float c[32];
#pragma unroll
    for (int p = 0; p < 4; ++p) {
        const float* L = logits + (size_t)p * QN8 + (size_t)q * 8;
#pragma unroll
        for (int j = 0; j < 8; ++j) c[p * 8 + j] = L[j];
    }
    float h[Kn], v[Kn];
#pragma unroll
    for (int k = 0; k < Kn; ++k) { h[k] = c[k]; v[k] = c[11 + k]; }

    float mh = h[0], mv = v[0];
#pragma unroll
    for (int k = 1; k < Kn; ++k) { mh = fmaxf(mh, h[k]); mv = fmaxf(mv, v[k]); }
    float sh = 0.f, sv = 0.f;
#pragma unroll
    for (int k = 0; k < Kn; ++k) {
        h[k] = __expf(h[k] - mh); sh += h[k];
        v[k] = __expf(v[k] - mv); sv += v[k];
    }
    const float ih = 1.f / sh, iv = 1.f / sv;
    float* oh = khI + (size_t)px * 12;
    float* ov = kvI + (size_t)px * 12;
#pragma unroll
    for (int k = 0; k < Kn; ++k) { oh[k] = h[k] * ih; ov[k] = v[k] * iv; }
    oh[11] = 0.f; ov[11] = 0.f;
}

// ---------------------------------------------------------------------------
// Horizontal 11-tap per-pixel filter (replicate pad), interleaved kh
// ---------------------------------------------------------------------------
__global__ __launch_bounds__(256) void hblur(
    const float* __restrict__ rgb, const float* __restrict__ khI,
    float* __restrict__ outh)
{
    const int px = blockIdx.x * 256 + threadIdx.x;
    const int y = px >> 9, x = px & (Wn - 1);
    const float* kp = khI + (size_t)px * 12;
    float kk[Kn];
#pragma unroll
    for (int k = 0; k < Kn; ++k) kk[k] = kp[k];

#pragma unroll
    for (int c = 0; c < 3; ++c) {
        const float* r = rgb + (size_t)c * HWn + (size_t)y * Wn;
        float s = 0.f;
#pragma unroll
        for (int k = 0; k < Kn; ++k) {
            int xx = x + k - PADk;
            xx = min(max(xx, 0), Wn - 1);
            s += r[xx] * kk[k];
        }
        outh[(size_t)c * HWn + px] = s;
    }
}

// ---------------------------------------------------------------------------
// Vertical 11-tap filter (replicate pad) + sigmoid-mask composite
// ---------------------------------------------------------------------------
__global__ __launch_bounds__(256) void vblur_compose(
    const float* __restrict__ outh, const float* __restrict__ kvI,
    const float* __restrict__ rgb, const float* __restrict__ depth,
    float* __restrict__ out)
{
    const int px = blockIdx.x * 256 + threadIdx.x;
    const int y = px >> 9, x = px & (Wn - 1);
    const float* kp = kvI + (size_t)px * 12;
    float kk[Kn];
#pragma unroll
    for (int k = 0; k < Kn; ++k) kk[k] = kp[k];

    const float d = depth[px];
    const float m = 1.f / (1.f + __expf(-(d - 0.2f) * 15.f));

#pragma unroll
    for (int c = 0; c < 3; ++c) {
        const float* col = outh + (size_t)c * HWn + x;
        float s = 0.f;
#pragma unroll
        for (int k = 0; k < Kn; ++k) {
            int yy = y + k - PADk;
            yy = min(max(yy, 0), Hn - 1);
            s += col[(size_t)yy * Wn] * kk[k];
        }
        const float r = rgb[(size_t)c * HWn + px];
        out[(size_t)c * HWn + px] = m * r + (1.f - m) * s;
    }
}

// ---------------------------------------------------------------------------
extern "C" void kernel_launch(void* const* d_in, const int* in_sizes, int n_in,
                              void* d_out, int out_size, void* d_ws, size_t ws_size,
                              hipStream_t stream)
{
    const float* rgb   = (const float*)d_in[0];
    const float* depth = (const float*)d_in[1];
    const float* w1 = (const float*)d_in[2];  const float* b1 = (const float*)d_in[3];
    const float* w2 = (const float*)d_in[4];  const float* b2 = (const float*)d_in[5];
    const float* w3 = (const float*)d_in[6];  const float* b3 = (const float*)d_in[7];
    const float* w4 = (const float*)d_in[8];  const float* b4 = (const float*)d_in[9];
    const float* w5 = (const float*)d_in[10]; const float* b5 = (const float*)d_in[11];
    const float* wh = (const float*)d_in[12]; const float* bh = (const float*)d_in[13];
    const float* wv = (const float*)d_in[14]; const float* bv = (const float*)d_in[15];

    char* ws = (char*)d_ws;
    size_t off = 0;
    auto alloc = [&](size_t bytes) -> void* {
        void* p = ws + off;
        off += (bytes + 255) & ~(size_t)255;
        return p;
    };

    // ~168.5 MB total
    bf16*  xin  = (bf16*)alloc((size_t)QN * 8   * 2);     //  4.2 MB (1 plane)
    bf16*  fA   = (bf16*)alloc((size_t)QN * 128 * 2);     // 67.6 MB (16 planes)
    bf16*  fB   = (bf16*)alloc((size_t)QN * 128 * 2);     // 67.6 MB (16 planes)
    float* khI  = (float*)alloc((size_t)HWn * 12 * 4);    // 12.6 MB
    float* kvI  = (float*)alloc((size_t)HWn * 12 * 4);    // 12.6 MB
    float* oh   = (float*)alloc((size_t)HWn * 3  * 4);    //  3.1 MB
    bf16*  wt1  = (bf16*)alloc(64  * 96   * 2);
    bf16*  wt2  = (bf16*)alloc(64  * 576  * 2);
    bf16*  wt3  = (bf16*)alloc(128 * 576  * 2);
    bf16*  wt4  = (bf16*)alloc(128 * 1152 * 2);
    bf16*  wt5  = (bf16*)alloc(64  * 1152 * 2);
    bf16*  wtHV = (bf16*)alloc(32  * 576  * 2);
    float* bHV  = (float*)alloc(32 * 4);
    float* logits = (float*)fB;   // alias: fB free when convhv runs (4 f32 planes)
    (void)ws_size;

    // weight prep into MFMA-fragment order (runs every launch)
    prep_wtF<<<(64 * 96   + 255) / 256, 256, 0, stream>>>(w1, wt1, 64, 4,   8,   12);
    prep_wtF<<<(64 * 576  + 255) / 256, 256, 0, stream>>>(w2, wt2, 64, 64,  64,  9);
    prep_wtF<<<(128* 576  + 255) / 256, 256, 0, stream>>>(w3, wt3, 128, 64, 64,  9);
    prep_wtF<<<(128* 1152 + 255) / 256, 256, 0, stream>>>(w4, wt4, 128, 128, 128, 9);
    prep_wtF<<<(64 * 1152 + 255) / 256, 256, 0, stream>>>(w5, wt5, 64, 128, 128, 9);
    prep_hvF<<<(32 * 576  + 255) / 256, 256, 0, stream>>>(wh, wv, wtHV);
    prep_bias_hv<<<1, 32, 0, stream>>>(bh, bv, bHV);

    constexpr int HALO_THREADS = 16 * (2 * Wp + 2 * Hn);   // 16 planes * 2052

    // fA halos are never corrupted during a launch -> zero once.
    zero_halo<<<(HALO_THREADS + 255) / 256, 256, 0, stream>>>(fA, 16);

    for (int b = 0; b < Bn; ++b) {
        const float* rgb_b   = rgb   + (size_t)b * 3 * HWn;
        const float* depth_b = depth + (size_t)b * HWn;
        float*       out_b   = (float*)d_out + (size_t)b * 3 * HWn;

        // fB halos ARE corrupted each batch by the logits (f32) alias.
        zero_halo<<<(HALO_THREADS + 255) / 256, 256, 0, stream>>>(fB, 16);

        pack8<<<(QN + 255) / 256, 256, 0, stream>>>(rgb_b, depth_b, xin);

        // <CINP, COUT, TAPSP, NFM, RELU, OUTF32>  grid = (512/BM, 512)
        conv_gemm<8,   64,  12, 4, true,  false><<<dim3(2, 512), 256, 0, stream>>>(xin, wt1, b1, fA);
        conv_gemm<64,  64,  9,  4, true,  false><<<dim3(2, 512), 256, 0, stream>>>(fA,  wt2, b2, fB);
        conv_gemm<64,  128, 9,  4, true,  false><<<dim3(4, 512), 256, 0, stream>>>(fB,  wt3, b3, fA);
        conv_gemm<128, 128, 9,  4, true,  false><<<dim3(4, 512), 256, 0, stream>>>(fA,  wt4, b4, fB);
        conv_gemm<128, 64,  9,  4, true,  false><<<dim3(2, 512), 256, 0, stream>>>(fB,  wt5, b5, fA);
        conv_gemm<64,  32,  9,  4, false, true ><<<dim3(2, 512), 256, 0, stream>>>(fA,  wtHV, bHV, logits);

        softmax_hv<<<HWn / 256, 256, 0, stream>>>(logits, khI, kvI);
        hblur<<<HWn / 256, 256, 0, stream>>>(rgb_b, khI, oh);
        vblur_compose<<<HWn / 256, 256, 0, stream>>>(oh, kvI, rgb_b, depth_b, out_b);
    }
}

// Round 11
// 1243.511 us; speedup vs baseline: 1.4775x; 1.4775x over previous
//
#include <hip/hip_runtime.h>
#include <hip/hip_bf16.h>

using bf16 = __hip_bfloat16;
typedef short bf16x8 __attribute__((ext_vector_type(8)));
typedef float f32x4  __attribute__((ext_vector_type(4)));

static constexpr int Bn = 4, Hn = 512, Wn = 512;
static constexpr int HWn = Hn * Wn;          // 262144
static constexpr int Hp = 514, Wp = 514;
static constexpr int QN = Hp * Wp;           // 264196 (1-px halo all around)
static constexpr int QN8 = QN * 8;           // elements per 8-channel plane
static constexpr int Kn = 11, PADk = 5;

__device__ __forceinline__ float b2f(bf16 v) { return __bfloat162float(v); }
__device__ __forceinline__ bf16  f2b(float v) { return __float2bfloat16(v); }

// ---------------------------------------------------------------------------
// Feature layout: plane-split NHW,C8 — [C/8 planes][QN pixels][8 ch] bf16.
// ---------------------------------------------------------------------------

// Zero the 1-px halo ring of every plane (2052 px/plane).
__global__ __launch_bounds__(256) void zero_halo(bf16* __restrict__ buf, int nplanes)
{
    constexpr int PER = 2 * Wp + 2 * Hn;     // 2052
    int i = blockIdx.x * 256 + threadIdx.x;
    if (i >= nplanes * PER) return;
    int p = i / PER, r = i - p * PER;
    int q;
    if (r < Wp)            q = r;                          // top row
    else if (r < 2 * Wp)   q = (Hp - 1) * Wp + (r - Wp);   // bottom row
    else if (r < 2 * Wp + Hn) q = (r - 2 * Wp + 1) * Wp;   // left col rows 1..512
    else                   q = (r - 2 * Wp - Hn + 1) * Wp + (Wp - 1); // right col
    *(uint4*)(buf + (size_t)p * QN8 + (size_t)q * 8) = uint4{0u, 0u, 0u, 0u};
}

// Pack concat(rgb, depth, 0,0,0,0) -> plane 0 of xin ([QN][8]); halo = 0.
__global__ __launch_bounds__(256) void pack8(
    const float* __restrict__ rgb, const float* __restrict__ depth,
    bf16* __restrict__ xin)
{
    int q = blockIdx.x * 256 + threadIdx.x;
    if (q >= QN) return;
    int yy = q / Wp, xx = q - yy * Wp;
    float r = 0.f, g = 0.f, b = 0.f, d = 0.f;
    if (yy >= 1 && yy <= Hn && xx >= 1 && xx <= Wn) {
        int px = (yy - 1) * Wn + (xx - 1);
        r = rgb[px]; g = rgb[HWn + px]; b = rgb[2 * HWn + px]; d = depth[px];
    }
    auto pk = [](float a, float c) {
        return (unsigned)__builtin_bit_cast(unsigned short, __float2bfloat16(a)) |
               ((unsigned)__builtin_bit_cast(unsigned short, __float2bfloat16(c)) << 16);
    };
    uint4 o; o.x = pk(r, g); o.y = pk(b, d); o.z = 0u; o.w = 0u;
    *(uint4*)(xin + (size_t)q * 8) = o;
}

// ---------------------------------------------------------------------------
// Weight prep: OIHW f32 -> MFMA-fragment-ordered bf16.
// dst[ ((ks*NCB + c16b)*64 + lane)*8 + j ] = wt[co][k] where
//   co = c16b*16 + (lane&15), k = ks*32 + (lane>>4)*8 + j, k = tap*CINP + ci.
// ---------------------------------------------------------------------------
__global__ void prep_wtF(const float* __restrict__ w, bf16* __restrict__ dst,
                         int COUT, int CIN, int CINP, int TAPSP)
{
    int K = CINP * TAPSP, NCB = COUT / 16;
    int idx = blockIdx.x * 256 + threadIdx.x;
    if (idx >= COUT * K) return;
    int j = idx & 7, lane = (idx >> 3) & 63;
    int rest = idx >> 9;
    int c16b = rest % NCB, ks = rest / NCB;
    int co = c16b * 16 + (lane & 15);
    int k  = ks * 32 + (lane >> 4) * 8 + j;
    int tap = k / CINP, ci = k - tap * CINP;
    float v = (tap < 9 && ci < CIN) ? w[((size_t)co * CIN + ci) * 9 + tap] : 0.f;
    dst[idx] = f2b(v);
}

// wh (rows 0-10) + wv (rows 11-21) + zero (22-31), fragment-ordered [32][576]
__global__ void prep_hvF(const float* __restrict__ wh, const float* __restrict__ wv,
                         bf16* __restrict__ dst)
{
    int idx = blockIdx.x * 256 + threadIdx.x;
    if (idx >= 32 * 576) return;
    int j = idx & 7, lane = (idx >> 3) & 63;
    int rest = idx >> 9;
    int c16b = rest & 1, ks = rest >> 1;       // NCB = 2
    int co = c16b * 16 + (lane & 15);
    int k  = ks * 32 + (lane >> 4) * 8 + j;
    int tap = k / 64, ci = k & 63;
    float v = 0.f;
    if (tap < 9) {
        if (co < 11)      v = wh[((size_t)co * 64 + ci) * 9 + tap];
        else if (co < 22) v = wv[((size_t)(co - 11) * 64 + ci) * 9 + tap];
    }
    dst[idx] = f2b(v);
}

__global__ void prep_bias_hv(const float* __restrict__ bh, const float* __restrict__ bv,
                             float* __restrict__ dst)
{
    int i = threadIdx.x;
    if (i < 32) dst[i] = (i < 11) ? bh[i] : ((i < 22) ? bv[i - 11] : 0.f);
}

// ---------------------------------------------------------------------------
// Implicit-GEMM 3x3 conv via MFMA 16x16x32 bf16 — BARRIER-FREE K-loop.
//   in:  plane-split [CINP/8][QN][8] bf16   out: plane-split [COUT/8][QN][8]
// Block: 256 thr = 4 waves. Wave tile: NFM*16 px x FULL COUT (round-9 shape:
// best measured locality/ILP balance; round-10's smaller tiles broke L2 row
// reuse, FETCH 109->212 MB). 2-deep register pipeline, no barriers.
// Round-11 micro-opts: s_setprio(1) around the MFMA cluster (waves drift
// freely -> role diversity, T5 regime) and larger load group issued first.
// Epilogue: LDS plane-major tile -> contiguous uint4 stores.
// ---------------------------------------------------------------------------
template<int CINP, int COUT, int TAPSP, int NFM, bool RELU, bool OUTF32>
__global__ __launch_bounds__(256, 2) void conv_gemm(
    const bf16* __restrict__ in, const bf16* __restrict__ wtF,
    const float* __restrict__ bias, void* __restrict__ outv)
{
    constexpr int K    = CINP * TAPSP;
    constexpr int NK   = K / 32;
    constexpr int NCB  = COUT / 16;
    constexpr int NFN  = NCB;                     // full-COUT wave tile
    constexpr int BM   = 4 * NFM * 16;            // 4 waves stacked on px
    constexpr int GX   = 512 / BM;
    constexpr int OSZ  = OUTF32 ? 4 : 2;
    constexpr int TILEB = BM * COUT * OSZ;
    constexpr int PCB  = BM * 8 * OSZ;            // bytes per output plane chunk

    __shared__ char smem[TILEB];                  // epilogue staging only

    const int tid  = threadIdx.x;
    const int lane = tid & 63, wid = tid >> 6;
    const int l15  = lane & 15, l4 = lane >> 4;

    // XCD-band swizzle: XCD k owns a contiguous band of rows (nwg % 8 == 0)
    const int nwg  = GX * 512;
    int orig = (int)blockIdx.y * GX + (int)blockIdx.x;
    int sbid = (orig & 7) * (nwg >> 3) + (orig >> 3);
    const int bx = (GX == 1) ? 0 : (sbid & (GX - 1));
    const int by = (GX == 1) ? sbid : (sbid / GX);

    const int qblk = (by + 1) * Wp + 1 + bx * BM;   // block's first pixel
    const int q0   = qblk + wid * (NFM * 16);       // wave's first pixel

    // A base element offsets per m-frag (plane term from l4 unless CINP==8)
    int abase[NFM];
#pragma unroll
    for (int mf = 0; mf < NFM; ++mf) {
        int q = q0 + mf * 16 + l15;
        abase[mf] = q * 8 + ((CINP == 8) ? 0 : l4 * QN8);
    }

    auto loadA = [&](int ks, bf16x8 (&a)[NFM]) {
        if constexpr (CINP == 8) {
            int tap = ks * 4 + l4;                 // per-lane tap
            int dy  = tap / 3;
            int off = (tap < 9) ? (dy - 1) * Wp + (tap - dy * 3 - 1) : 0;
#pragma unroll
            for (int mf = 0; mf < NFM; ++mf)
                a[mf] = *(const bf16x8*)(in + abase[mf] + off * 8);
        } else {
            const int kk  = ks * 32;
            const int tap = kk / CINP;
            const int cib = kk - tap * CINP;
            const int pb  = cib >> 3;              // base plane of this k-chunk
            const int dy  = tap / 3;
            const int off = (dy - 1) * Wp + (tap - dy * 3 - 1);
            const int stp = pb * QN8 + off * 8;
#pragma unroll
            for (int mf = 0; mf < NFM; ++mf)
                a[mf] = *(const bf16x8*)(in + abase[mf] + stp);
        }
    };
    auto loadB = [&](int ks, bf16x8 (&bfr)[NFN]) {
        const bf16* bp = wtF + lane * 8;
#pragma unroll
        for (int nf = 0; nf < NFN; ++nf)
            bfr[nf] = *(const bf16x8*)(bp + (ks * NCB + nf) * 512);
    };
    // issue the LARGER load group first (longer queue time -> longer lead)
    auto loadAB = [&](int ks, bf16x8 (&a)[NFM], bf16x8 (&bfr)[NFN]) {
        if constexpr (NFN >= NFM) { loadB(ks, bfr); loadA(ks, a); }
        else                      { loadA(ks, a);   loadB(ks, bfr); }
    };

    f32x4 acc[NFM][NFN];
#pragma unroll
    for (int mf = 0; mf < NFM; ++mf)
#pragma unroll
        for (int nf = 0; nf < NFN; ++nf) acc[mf][nf] = f32x4{0.f, 0.f, 0.f, 0.f};

    auto step = [&](bf16x8 (&a)[NFM], bf16x8 (&bfr)[NFN]) {
        __builtin_amdgcn_s_setprio(1);
#pragma unroll
        for (int mf = 0; mf < NFM; ++mf)
#pragma unroll
            for (int nf = 0; nf < NFN; ++nf)
                acc[mf][nf] = __builtin_amdgcn_mfma_f32_16x16x32_bf16(
                    a[mf], bfr[nf], acc[mf][nf], 0, 0, 0);
        __builtin_amdgcn_s_setprio(0);
    };

    // 2-deep register pipeline, named double buffers, NO barriers.
    bf16x8 a0[NFM], a1[NFM], b0[NFN], b1[NFN];
    loadAB(0, a0, b0);
    for (int ks = 0; ks + 1 < NK; ks += 2) {
        loadAB(ks + 1, a1, b1);
        step(a0, b0);
        if (ks + 2 < NK) loadAB(ks + 2, a0, b0);
        step(a1, b1);
    }
    if constexpr (NK & 1) step(a0, b0);

    // ---- epilogue: bias (+relu) -> LDS plane-major tile -> chunk stores ----
#pragma unroll
    for (int nf = 0; nf < NFN; ++nf) {
        const int co = nf * 16 + l15;
        const float bv = bias[co];
#pragma unroll
        for (int mf = 0; mf < NFM; ++mf) {
#pragma unroll
            for (int r = 0; r < 4; ++r) {
                float v = acc[mf][nf][r] + bv;
                if constexpr (RELU) v = fmaxf(v, 0.f);
                const int pl = wid * (NFM * 16) + mf * 16 + l4 * 4 + r;  // local px
                const int eo = ((co >> 3) * BM + pl) * 8 + (co & 7);
                if constexpr (OUTF32)
                    ((float*)smem)[eo] = v;
                else
                    ((bf16*)smem)[eo] = f2b(v);
            }
        }
    }
    __syncthreads();
    // each output plane chunk = BM consecutive pixels x 8 ch = contiguous span
    char* gbase = (char*)outv;
    for (int ofs = tid * 16; ofs < TILEB; ofs += 4096) {
        const int p = ofs / PCB, w = ofs - p * PCB;
        char* dst = gbase + ((size_t)p * QN8 + (size_t)qblk * 8) * OSZ + w;
        *(uint4*)dst = *(const uint4*)(smem + ofs);
    }
}

// ---------------------------------------------------------------------------
// Softmax over the 11+11 logit channels (4 f32 planes) -> [px][12] f32 maps
// ---------------------------------------------------------------------------
__global__ __launch_bounds__(256) void softmax_hv(
    const float* __restrict__ logits, float* __restrict__ khI, float* __restrict__ kvI)
{
    int px = blockIdx.x * 256 + threadIdx.x;   // over HW exact
    int y = px >> 9, x = px & (Wn - 1);
    int q = (y + 1) * Wp + x + 1;
    float c[32];
#pragma unroll
    for (int p = 0; p < 4; ++p) {
        const float* L = logits + (size_t)p * QN8 + (size_t)q * 8;
#pragma unroll
        for (int j = 0; j < 8; ++j) c[p * 8 + j] = L[j];
    }
    float h[Kn], v[Kn];
#pragma unroll
    for (int k = 0; k < Kn; ++k) { h[k] = c[k]; v[k] = c[11 + k]; }

    float mh = h[0], mv = v[0];
#pragma unroll
    for (int k = 1; k < Kn; ++k) { mh = fmaxf(mh, h[k]); mv = fmaxf(mv, v[k]); }
    float sh = 0.f, sv = 0.f;
#pragma unroll
    for (int k = 0; k < Kn; ++k) {
        h[k] = __expf(h[k] - mh); sh += h[k];
        v[k] = __expf(v[k] - mv); sv += v[k];
    }
    const float ih = 1.f / sh, iv = 1.f / sv;
    float* oh = khI + (size_t)px * 12;
    float* ov = kvI + (size_t)px * 12;
#pragma unroll
    for (int k = 0; k < Kn; ++k) { oh[k] = h[k] * ih; ov[k] = v[k] * iv; }
    oh[11] = 0.f; ov[11] = 0.f;
}

// ---------------------------------------------------------------------------
// Horizontal 11-tap per-pixel filter (replicate pad), interleaved kh
// ---------------------------------------------------------------------------
__global__ __launch_bounds__(256) void hblur(
    const float* __restrict__ rgb, const float* __restrict__ khI,
    float* __restrict__ outh)
{
    const int px = blockIdx.x * 256 + threadIdx.x;
    const int y = px >> 9, x = px & (Wn - 1);
    const float* kp = khI + (size_t)px * 12;
    float kk[Kn];
#pragma unroll
    for (int k = 0; k < Kn; ++k) kk[k] = kp[k];

#pragma unroll
    for (int c = 0; c < 3; ++c) {
        const float* r = rgb + (size_t)c * HWn + (size_t)y * Wn;
        float s = 0.f;
#pragma unroll
        for (int k = 0; k < Kn; ++k) {
            int xx = x + k - PADk;
            xx = min(max(xx, 0), Wn - 1);
            s += r[xx] * kk[k];
        }
        outh[(size_t)c * HWn + px] = s;
    }
}

// ---------------------------------------------------------------------------
// Vertical 11-tap filter (replicate pad) + sigmoid-mask composite
// ---------------------------------------------------------------------------
__global__ __launch_bounds__(256) void vblur_compose(
    const float* __restrict__ outh, const float* __restrict__ kvI,
    const float* __restrict__ rgb, const float* __restrict__ depth,
    float* __restrict__ out)
{
    const int px = blockIdx.x * 256 + threadIdx.x;
    const int y = px >> 9, x = px & (Wn - 1);
    const float* kp = kvI + (size_t)px * 12;
    float kk[Kn];
#pragma unroll
    for (int k = 0; k < Kn; ++k) kk[k] = kp[k];

    const float d = depth[px];
    const float m = 1.f / (1.f + __expf(-(d - 0.2f) * 15.f));

#pragma unroll
    for (int c = 0; c < 3; ++c) {
        const float* col = outh + (size_t)c * HWn + x;
        float s = 0.f;
#pragma unroll
        for (int k = 0; k < Kn; ++k) {
            int yy = y + k - PADk;
            yy = min(max(yy, 0), Hn - 1);
            s += col[(size_t)yy * Wn] * kk[k];
        }
        const float r = rgb[(size_t)c * HWn + px];
        out[(size_t)c * HWn + px] = m * r + (1.f - m) * s;
    }
}

// ---------------------------------------------------------------------------
extern "C" void kernel_launch(void* const* d_in, const int* in_sizes, int n_in,
                              void* d_out, int out_size, void* d_ws, size_t ws_size,
                              hipStream_t stream)
{
    const float* rgb   = (const float*)d_in[0];
    const float* depth = (const float*)d_in[1];
    const float* w1 = (const float*)d_in[2];  const float* b1 = (const float*)d_in[3];
    const float* w2 = (const float*)d_in[4];  const float* b2 = (const float*)d_in[5];
    const float* w3 = (const float*)d_in[6];  const float* b3 = (const float*)d_in[7];
    const float* w4 = (const float*)d_in[8];  const float* b4 = (const float*)d_in[9];
    const float* w5 = (const float*)d_in[10]; const float* b5 = (const float*)d_in[11];
    const float* wh = (const float*)d_in[12]; const float* bh = (const float*)d_in[13];
    const float* wv = (const float*)d_in[14]; const float* bv = (const float*)d_in[15];

    char* ws = (char*)d_ws;
    size_t off = 0;
    auto alloc = [&](size_t bytes) -> void* {
        void* p = ws + off;
        off += (bytes + 255) & ~(size_t)255;
        return p;
    };

    // ~168.5 MB total
    bf16*  xin  = (bf16*)alloc((size_t)QN * 8   * 2);     //  4.2 MB (1 plane)
    bf16*  fA   = (bf16*)alloc((size_t)QN * 128 * 2);     // 67.6 MB (16 planes)
    bf16*  fB   = (bf16*)alloc((size_t)QN * 128 * 2);     // 67.6 MB (16 planes)
    float* khI  = (float*)alloc((size_t)HWn * 12 * 4);    // 12.6 MB
    float* kvI  = (float*)alloc((size_t)HWn * 12 * 4);    // 12.6 MB
    float* oh   = (float*)alloc((size_t)HWn * 3  * 4);    //  3.1 MB
    bf16*  wt1  = (bf16*)alloc(64  * 96   * 2);
    bf16*  wt2  = (bf16*)alloc(64  * 576  * 2);
    bf16*  wt3  = (bf16*)alloc(128 * 576  * 2);
    bf16*  wt4  = (bf16*)alloc(128 * 1152 * 2);
    bf16*  wt5  = (bf16*)alloc(64  * 1152 * 2);
    bf16*  wtHV = (bf16*)alloc(32  * 576  * 2);
    float* bHV  = (float*)alloc(32 * 4);
    float* logits = (float*)fB;   // alias: fB free when convhv runs (4 f32 planes)
    (void)ws_size;

    // weight prep into MFMA-fragment order (runs every launch)
    prep_wtF<<<(64 * 96   + 255) / 256, 256, 0, stream>>>(w1, wt1, 64, 4,   8,   12);
    prep_wtF<<<(64 * 576  + 255) / 256, 256, 0, stream>>>(w2, wt2, 64, 64,  64,  9);
    prep_wtF<<<(128* 576  + 255) / 256, 256, 0, stream>>>(w3, wt3, 128, 64, 64,  9);
    prep_wtF<<<(128* 1152 + 255) / 256, 256, 0, stream>>>(w4, wt4, 128, 128, 128, 9);
    prep_wtF<<<(64 * 1152 + 255) / 256, 256, 0, stream>>>(w5, wt5, 64, 128, 128, 9);
    prep_hvF<<<(32 * 576  + 255) / 256, 256, 0, stream>>>(wh, wv, wtHV);
    prep_bias_hv<<<1, 32, 0, stream>>>(bh, bv, bHV);

    constexpr int HALO_THREADS = 16 * (2 * Wp + 2 * Hn);   // 16 planes * 2052

    // fA halos are never corrupted during a launch -> zero once.
    zero_halo<<<(HALO_THREADS + 255) / 256, 256, 0, stream>>>(fA, 16);

    for (int b = 0; b < Bn; ++b) {
        const float* rgb_b   = rgb   + (size_t)b * 3 * HWn;
        const float* depth_b = depth + (size_t)b * HWn;
        float*       out_b   = (float*)d_out + (size_t)b * 3 * HWn;

        // fB halos ARE corrupted each batch by the logits (f32) alias.
        zero_halo<<<(HALO_THREADS + 255) / 256, 256, 0, stream>>>(fB, 16);

        pack8<<<(QN + 255) / 256, 256, 0, stream>>>(rgb_b, depth_b, xin);

        // <CINP, COUT, TAPSP, NFM, RELU, OUTF32>  grid = (512/(64*NFM), 512)
        conv_gemm<8,   64,  12, 4, true,  false><<<dim3(2, 512), 256, 0, stream>>>(xin, wt1, b1, fA);
        conv_gemm<64,  64,  9,  8, true,  false><<<dim3(1, 512), 256, 0, stream>>>(fA,  wt2, b2, fB);
        conv_gemm<64,  128, 9,  4, true,  false><<<dim3(2, 512), 256, 0, stream>>>(fB,  wt3, b3, fA);
        conv_gemm<128, 128, 9,  4, true,  false><<<dim3(2, 512), 256, 0, stream>>>(fA,  wt4, b4, fB);
        conv_gemm<128, 64,  9,  8, true,  false><<<dim3(1, 512), 256, 0, stream>>>(fB,  wt5, b5, fA);
        conv_gemm<64,  32,  9,  4, false, true ><<<dim3(2, 512), 256, 0, stream>>>(fA,  wtHV, bHV, logits);

        softmax_hv<<<HWn / 256, 256, 0, stream>>>(logits, khI, kvI);
        hblur<<<HWn / 256, 256, 0, stream>>>(rgb_b, khI, oh);
        vblur_compose<<<HWn / 256, 256, 0, stream>>>(oh, kvI, rgb_b, depth_b, out_b);
    }
}